// Round 5
// baseline (350.727 us; speedup 1.0000x reference)
//
#include <hip/hip_runtime.h>
#include <stdint.h>
#include <math.h>

typedef unsigned short u16;
typedef __attribute__((ext_vector_type(8))) short short8;
typedef __attribute__((ext_vector_type(8))) _Float16 half8;
typedef __attribute__((ext_vector_type(4))) float float4v;
typedef __attribute__((ext_vector_type(16))) float float16v;
typedef __attribute__((ext_vector_type(4))) u16 ushort4v;

#define T_SEQ 2048
#define NB 2
#define NE 2048
#define NH 16
#define NKV 4
#define HD 128
#define KDIM 2048

union Frag { short8 s; half8 h; };

__device__ inline u16 f32_bf16(float f) {
    union { float f; uint32_t u; } v; v.f = f;
    uint32_t u = v.u;
    return (u16)((u + 0x7fffu + ((u >> 16) & 1u)) >> 16);
}
__device__ inline u16 f32_f16(float f) {
    union { _Float16 h; u16 u; } v; v.h = (_Float16)f;
    return v.u;
}

// v_cvt_pk_bf16_f32: dst.lo = bf16(lo), dst.hi = bf16(hi)  (RNE)
__device__ inline uint32_t cvtpk_bf16(float lo, float hi) {
    uint32_t r;
    asm("v_cvt_pk_bf16_f32 %0, %1, %2" : "=v"(r) : "v"(lo), "v"(hi));
    return r;
}
// v_permlane32_swap_b32: a.lanes[32+i] <-> b.lanes[i]
// after: a = [a.lo | b.lo], b = [a.hi | b.hi]
__device__ inline void perm32swap(uint32_t& a, uint32_t& b) {
    asm("v_permlane32_swap_b32 %0, %1" : "+v"(a), "+v"(b));
}

// async global->LDS, 16B per lane; LDS dest = wave-uniform base + lane*16
typedef __attribute__((address_space(1))) const void g_void;
typedef __attribute__((address_space(3))) void l_void;
#define GLOAD16(g, l) __builtin_amdgcn_global_load_lds((g_void*)(g), (l_void*)(l), 16, 0, 0)

// ---------------- conversion kernels ----------------
__global__ void conv_f16(const float* __restrict__ in, u16* __restrict__ out) {
    int i = blockIdx.x * blockDim.x + threadIdx.x;
    float4 v = ((const float4*)in)[i];
    ushort4v o;
    o.x = f32_f16(v.x); o.y = f32_f16(v.y); o.z = f32_f16(v.z); o.w = f32_f16(v.w);
    *(ushort4v*)(out + (size_t)i * 4) = o;
}

template<bool TO_F16>
__global__ void transpose_convert(const float* __restrict__ in, u16* __restrict__ out,
                                  int K, int N) {
    __shared__ float tile[32][33];
    int n0 = blockIdx.x * 32, k0 = blockIdx.y * 32;
    int tx = threadIdx.x, ty = threadIdx.y;   // 32 x 8
    for (int i = 0; i < 32; i += 8)
        tile[ty + i][tx] = in[(size_t)(k0 + ty + i) * N + n0 + tx];
    __syncthreads();
    for (int i = 0; i < 32; i += 8) {
        float v = tile[tx][ty + i];
        out[(size_t)(n0 + ty + i) * K + k0 + tx] = TO_F16 ? f32_f16(v) : f32_bf16(v);
    }
}

__global__ void rope_tab(float* __restrict__ ctab, float* __restrict__ stab) {
    int i = blockIdx.x * blockDim.x + threadIdx.x;   // < 2048*64
    int t = i >> 6, j = i & 63;
    float freqf = (float)pow(10000.0, -(double)j / 1024.0);
    float angf = (float)t * freqf;          // fp32 rounding like np.outer
    double a = (double)angf;
    ctab[i] = (float)cos(a);
    stab[i] = (float)sin(a);
}

// ---------------- GEMM main loop: 2-phase double-buffered (T3 minimum form) ----------------
// R4 counters: 2-barrier loop exposed the full gload_lds latency every K-step
// (drain immediately after issue) -> MfmaUtil 21%, 510 TF. 2-phase: stage tile
// t+1 into buf^1 BEFORE computing tile t; ONE __syncthreads per K-step (its
// compiler-emitted vmcnt(0) drains loads that had the whole MFMA phase to
// complete). Race-safe with a single barrier: a wave can only stage buf^1
// after passing the previous barrier, which requires all waves done reading it.
// LDS linear [128][32] u16 per buffer (global_load_lds needs contiguous dest).
#define GEMM_STAGE_DECL(Asrc, Bsrc) \
    int rin = lane >> 2, ksl = lane & 3; \
    int u0r = wid * 32; \
    const u16* Ag0 = (Asrc) + (size_t)(m0 + u0r + rin) * KDIM + ksl * 8; \
    const u16* Ag1 = (Asrc) + (size_t)(m0 + u0r + 16 + rin) * KDIM + ksl * 8; \
    const u16* Bg0 = (Bsrc) + (size_t)(n0 + u0r + rin) * KDIM + ksl * 8; \
    const u16* Bg1 = (Bsrc) + (size_t)(n0 + u0r + 16 + rin) * KDIM + ksl * 8;

#define GEMM_STAGE(buf, kk) \
    GLOAD16(Ag0 + (kk), &Alds[buf][u0r * 32]); \
    GLOAD16(Ag1 + (kk), &Alds[buf][(u0r + 16) * 32]); \
    GLOAD16(Bg0 + (kk), &Blds[buf][u0r * 32]); \
    GLOAD16(Bg1 + (kk), &Blds[buf][(u0r + 16) * 32]);

#define GEMM_MAINLOOP(F16) \
    GEMM_STAGE(0, 0) \
    __syncthreads(); \
    { int cur = 0; \
    for (int k0 = 0; k0 < KDIM; k0 += 32) { \
        if (k0 + 32 < KDIM) { GEMM_STAGE(cur ^ 1, k0 + 32) } \
        Frag af[4], bf[4]; \
        for (int i = 0; i < 4; i++) \
            af[i].s = *(const short8*)&Alds[cur][(wr * 64 + i * 16 + l16) * 32 + quad * 8]; \
        for (int j = 0; j < 4; j++) \
            bf[j].s = *(const short8*)&Blds[cur][(wc * 64 + j * 16 + l16) * 32 + quad * 8]; \
        for (int i = 0; i < 4; i++) \
            for (int j = 0; j < 4; j++) { \
                if (F16) \
                    acc[i][j] = __builtin_amdgcn_mfma_f32_16x16x32_f16(af[i].h, bf[j].h, acc[i][j], 0, 0, 0); \
                else \
                    acc[i][j] = __builtin_amdgcn_mfma_f32_16x16x32_bf16(af[i].s, bf[j].s, acc[i][j], 0, 0, 0); \
            } \
        __syncthreads(); \
        cur ^= 1; \
    } }

// ---------------- fused Q+K+V projection: 1D grid of 768 equal-cost blocks ----------------
// lin <  512: Q:  C[t,d] = xh @ wqt^T, rope -> [B,NH,T,D]
// 512..639 : K:  C[t,d] = xh @ wkt^T, rope -> [B,NKV,T,D]
// 640..767 : V^T by operand swap: A = wvt (rows d=512), Bt = xh (rows t=4096)
//            -> C[d,t], write [B,NKV,D,T] coalesced along t (avoids the 47x
//            store-side write amplification measured in R1).
__global__ __launch_bounds__(256)
void gemm_qkv(const u16* __restrict__ xh, const u16* __restrict__ wqt,
              const u16* __restrict__ wkt, const u16* __restrict__ wvt,
              const float* __restrict__ bq, const float* __restrict__ bk,
              const float* __restrict__ bv,
              u16* __restrict__ qout, u16* __restrict__ kout, u16* __restrict__ vout,
              const float* __restrict__ ctab, const float* __restrict__ stab) {
    __shared__ u16 Alds[2][128 * 32];
    __shared__ u16 Blds[2][128 * 32];
    int tid = threadIdx.x;
    int wid = tid >> 6, lane = tid & 63;
    int quad = lane >> 4, l16 = lane & 15;
    int wr = wid >> 1, wc = wid & 1;

    int lin = blockIdx.x;
    int mode, m0, n0;
    const u16 *A, *Bt;
    if (lin < 512) {          // Q
        mode = 0; m0 = (lin >> 4) * 128; n0 = (lin & 15) * 128; A = xh; Bt = wqt;
    } else if (lin < 640) {   // K
        int i = lin - 512;
        mode = 1; m0 = (i >> 2) * 128; n0 = (i & 3) * 128; A = xh; Bt = wkt;
    } else {                  // V (swapped)
        int i = lin - 640;
        mode = 2; m0 = (i & 3) * 128; n0 = (i >> 2) * 128; A = wvt; Bt = xh;
    }

    float4v acc[4][4];
    for (int i = 0; i < 4; i++) for (int j = 0; j < 4; j++) acc[i][j] = (float4v){0,0,0,0};

    GEMM_STAGE_DECL(A, Bt)
    GEMM_MAINLOOP(true)

    if (mode == 2) {
        // rows m = global d (h = m>>7, d = m&127); cols = global t (b = col>>11)
        for (int i = 0; i < 4; i++) {
            int mbase = m0 + wr * 64 + i * 16 + quad * 4;
            float brow[4];
            for (int r = 0; r < 4; r++) brow[r] = bv[mbase + r];
            for (int j = 0; j < 4; j++) {
                int col = n0 + wc * 64 + j * 16 + l16;
                int b = col >> 11, t = col & 2047;
                for (int r = 0; r < 4; r++) {
                    int m = mbase + r;
                    float val = acc[i][j][r] + brow[r];
                    vout[(((size_t)(b * NKV + (m >> 7))) * HD + (m & 127)) * T_SEQ + t] = f32_bf16(val);
                }
            }
        }
    } else {
        const float* bias = mode ? bk : bq;
        u16* outU = mode ? kout : qout;
        int nheads = mode ? NKV : NH;
        for (int i = 0; i < 4; i++) {
            int mbase = m0 + wr * 64 + i * 16 + quad * 4;
            for (int j = 0; j < 4; j++) {
                int col = n0 + wc * 64 + j * 16 + l16;
                float bcol = bias[col];
                for (int r = 0; r < 4; r++) {
                    int m = mbase + r;
                    float val = acc[i][j][r] + bcol;
                    int b = m >> 11, t = m & 2047;
                    int h = col >> 7, d = col & 127;
                    int jj = d >> 1;
                    float c = ctab[t * 64 + jj];
                    float s = stab[t * 64 + jj];
                    float partner = __shfl_xor(val, 1, 64);
                    float o = (d & 1) ? (partner * s + val * c) : (val * c - partner * s);
                    outU[(((size_t)(b * nheads + h)) * T_SEQ + t) * HD + d] = f32_bf16(o);
                }
            }
        }
    }
}

// ---------------- output projection GEMM (bf16 in, fp32 + bias out) ----------------
__global__ __launch_bounds__(256)
void gemm_out(const u16* __restrict__ A, const u16* __restrict__ Bt,
              const float* __restrict__ bias, float* __restrict__ outF) {
    __shared__ u16 Alds[2][128 * 32];
    __shared__ u16 Blds[2][128 * 32];
    int tid = threadIdx.x;
    int wid = tid >> 6, lane = tid & 63;
    int quad = lane >> 4, l16 = lane & 15;
    int wr = wid >> 1, wc = wid & 1;
    int m0 = blockIdx.x * 128, n0 = blockIdx.y * 128;

    float4v acc[4][4];
    for (int i = 0; i < 4; i++) for (int j = 0; j < 4; j++) acc[i][j] = (float4v){0,0,0,0};

    GEMM_STAGE_DECL(A, Bt)
    GEMM_MAINLOOP(false)

    for (int i = 0; i < 4; i++) {
        int mbase = m0 + wr * 64 + i * 16 + quad * 4;
        for (int j = 0; j < 4; j++) {
            int col = n0 + wc * 64 + j * 16 + l16;
            float bcol = bias[col];
            for (int r = 0; r < 4; r++)
                outF[(size_t)(mbase + r) * NE + col] = acc[i][j][r] + bcol;
        }
    }
}

// ---------------- flash attention v4 ----------------
// v3h + (T12) in-register P via cvt_pk+permlane32_swap (plds removed: -18.4KB
// LDS, -1 barrier/tile), (T13) defer-max THR=8, (T5) setprio around MFMA
// clusters, fully-masked diagonal-tile skip for waves 0,1.
__global__ __launch_bounds__(256, 2)
void attn_kernel(const u16* __restrict__ Qr, const u16* __restrict__ Kr,
                 const u16* __restrict__ Vt, u16* __restrict__ Oout) {
    __shared__ u16 smem[17920];            // 35840 B
    u16* klds = smem;                      // K tile [s=64][d=128] stride 136
    u16* vlds = smem + 8704;               // V^T tile [d=128][s=64] stride 72
    int tid = threadIdx.x;
    int wid = tid >> 6, lane = tid & 63;
    int l32 = lane & 31, hh = lane >> 5;

    int lin = blockIdx.x + (blockIdx.y << 4);
    int g = lin >> 5, bh = lin & 31;
    int qt = (lin < 256) ? (15 - g) : (g - 8);   // balance: CU gets qt and 15-qt
    int b = bh >> 4, hd = bh & 15, kvh = hd >> 2;
    int t0 = qt * 128;

    const u16* Qb = Qr + (((size_t)(b * NH + hd)) * T_SEQ + t0 + wid * 32) * HD;
    const u16* Kb = Kr + ((size_t)(b * NKV + kvh)) * T_SEQ * HD;
    const u16* Vb = Vt + ((size_t)(b * NKV + kvh)) * HD * T_SEQ;

    // Q as B-operand frags: col = t = l32, k = d
    short8 qf[8];
#pragma unroll
    for (int ks = 0; ks < 8; ks++)
        qf[ks] = *(const short8*)(Qb + (size_t)l32 * HD + ks * 16 + hh * 8);

    float16v oacc[4];   // O^T: rows d (dt*32 block), cols t (= l32)
#pragma unroll
    for (int dt = 0; dt < 4; dt++)
        oacc[dt] = (float16v){0,0,0,0,0,0,0,0,0,0,0,0,0,0,0,0};
    float m_run = -INFINITY, l_run = 0.f;

    int ksr = tid >> 2, kc = (tid & 3) * 32;   // K staging: row s, col base (u16)
    int vdr = tid >> 1, vc = (tid & 1) * 32;   // V staging: row d, col base (u16)

    int nst = 2 * qt + 2;

    {   // prologue: stage tile 0
        const u16* ksrc = Kb + (size_t)ksr * HD + kc;
        const u16* vsrc = Vb + (size_t)vdr * T_SEQ + vc;
        short8 kr0[4], vr0[4];
#pragma unroll
        for (int i = 0; i < 4; i++) kr0[i] = *(const short8*)(ksrc + i * 8);
#pragma unroll
        for (int i = 0; i < 4; i++) vr0[i] = *(const short8*)(vsrc + i * 8);
#pragma unroll
        for (int i = 0; i < 4; i++) *(short8*)&klds[ksr * 136 + kc + i * 8] = kr0[i];
#pragma unroll
        for (int i = 0; i < 4; i++) *(short8*)&vlds[vdr * 72 + vc + i * 8] = vr0[i];
    }
    __syncthreads();

    for (int st = 0; st < nst; st++) {
        short8 krg[4], vrg[4];
        bool more = (st + 1 < nst);
        if (more) {   // prefetch next K/V tile into registers
            const u16* ksrc = Kb + ((size_t)(st + 1) * 64 + ksr) * HD + kc;
            const u16* vsrc = Vb + (size_t)vdr * T_SEQ + (st + 1) * 64 + vc;
#pragma unroll
            for (int i = 0; i < 4; i++) krg[i] = *(const short8*)(ksrc + i * 8);
#pragma unroll
            for (int i = 0; i < 4; i++) vrg[i] = *(const short8*)(vsrc + i * 8);
        }

        // wave-uniform skip: tile entirely above this wave's causal diagonal
        // (only st == 2qt+1 for waves 0,1). Barriers stay outside.
        bool active = (st * 64) <= (t0 + wid * 32 + 31);
        if (active) {
            // S^T = K * Q^T : rows = s (2 tiles of 32), cols = t (32)
            float16v sfa[2];
            sfa[0] = (float16v){0,0,0,0,0,0,0,0,0,0,0,0,0,0,0,0};
            sfa[1] = (float16v){0,0,0,0,0,0,0,0,0,0,0,0,0,0,0,0};
            __builtin_amdgcn_s_setprio(1);
#pragma unroll
            for (int ks = 0; ks < 8; ks++) {
                short8 kf0 = *(const short8*)&klds[l32 * 136 + ks * 16 + hh * 8];
                short8 kf1 = *(const short8*)&klds[(32 + l32) * 136 + ks * 16 + hh * 8];
                sfa[0] = __builtin_amdgcn_mfma_f32_32x32x16_bf16(kf0, qf[ks], sfa[0], 0, 0, 0);
                sfa[1] = __builtin_amdgcn_mfma_f32_32x32x16_bf16(kf1, qf[ks], sfa[1], 0, 0, 0);
            }
            __builtin_amdgcn_s_setprio(0);

            int tg = t0 + wid * 32 + l32;
            if (st >= 2 * qt) {   // causal mask on diagonal tiles
#pragma unroll
                for (int stile = 0; stile < 2; stile++)
#pragma unroll
                    for (int r = 0; r < 16; r++) {
                        int s = st * 64 + stile * 32 + (r & 3) + 8 * (r >> 2) + 4 * hh;
                        if (s > tg) sfa[stile][r] = -INFINITY;
                    }
            }

            // online softmax over s; T13 defer-max: skip O-rescale while the
            // tile max stays within 8 of the running max (P bounded by e^8).
            float mx = -INFINITY;
#pragma unroll
            for (int stile = 0; stile < 2; stile++)
#pragma unroll
                for (int r = 0; r < 16; r++) mx = fmaxf(mx, sfa[stile][r]);
            mx = fmaxf(mx, __shfl_xor(mx, 32, 64));
            bool nos = __all(mx - m_run <= 8.f);   // wave-uniform
            float mnew = nos ? m_run : fmaxf(m_run, mx);
            float alpha = nos ? 1.f : __expf(m_run - mnew);
            float psum = 0.f;
#pragma unroll
            for (int stile = 0; stile < 2; stile++)
#pragma unroll
                for (int r = 0; r < 16; r++) {
                    float p = __expf(sfa[stile][r] - mnew);
                    sfa[stile][r] = p;
                    psum += p;
                }
            psum += __shfl_xor(psum, 32, 64);
            l_run = l_run * alpha + psum;
            m_run = mnew;

            if (!nos) {
#pragma unroll
                for (int dt = 0; dt < 4; dt++)
#pragma unroll
                    for (int r = 0; r < 16; r++) oacc[dt][r] *= alpha;
            }

            // T12: P^T -> B-operand fragments entirely in registers.
            // Accumulator holds s_local=(r&3)+8(r>>2)+4hh; the B-operand needs
            // k=s=hh*8+e per 16-block. swap(P0,P2)/(P1,P3) redistributes the
            // 4-element groups across the lane halves: after swap,
            // P0=[lo|lo'], P2=[hi|hi'] which is exactly word0/word2 for both hh.
            __builtin_amdgcn_s_setprio(1);
#pragma unroll
            for (int g2 = 0; g2 < 4; g2++) {           // s16-block = ks2
                int stile = g2 >> 1, gg = g2 & 1;
                uint32_t P0 = cvtpk_bf16(sfa[stile][8 * gg + 0], sfa[stile][8 * gg + 1]);
                uint32_t P1 = cvtpk_bf16(sfa[stile][8 * gg + 2], sfa[stile][8 * gg + 3]);
                uint32_t P2 = cvtpk_bf16(sfa[stile][8 * gg + 4], sfa[stile][8 * gg + 5]);
                uint32_t P3 = cvtpk_bf16(sfa[stile][8 * gg + 6], sfa[stile][8 * gg + 7]);
                perm32swap(P0, P2);
                perm32swap(P1, P3);
                union { uint32_t w[4]; short8 s; } pf;
                pf.w[0] = P0; pf.w[1] = P1; pf.w[2] = P2; pf.w[3] = P3;
#pragma unroll
                for (int dt = 0; dt < 4; dt++) {
                    short8 vf = *(const short8*)&vlds[(dt * 32 + l32) * 72 + g2 * 16 + hh * 8];
                    oacc[dt] = __builtin_amdgcn_mfma_f32_32x32x16_bf16(vf, pf.s, oacc[dt], 0, 0, 0);
                }
            }
            __builtin_amdgcn_s_setprio(0);
        }

        __syncthreads();   // all K/V reads done before overwrite
        if (more) {
#pragma unroll
            for (int i = 0; i < 4; i++) *(short8*)&klds[ksr * 136 + kc + i * 8] = krg[i];
#pragma unroll
            for (int i = 0; i < 4; i++) *(short8*)&vlds[vdr * 72 + vc + i * 8] = vrg[i];
        }
        __syncthreads();   // staging visible before next iteration's reads
    }

    // epilogue: scale (per-lane), transpose O^T -> O via LDS scratch
    const float scale = 0.022097086912079608f;   // 2048^-0.5
    float sc = scale / l_run;
    u16* ow = smem + wid * 4352;           // [t=32][d=128] stride 136
#pragma unroll
    for (int dt = 0; dt < 4; dt++)
#pragma unroll
        for (int gq = 0; gq < 4; gq++) {
            ushort4v pk;
            pk.x = f32_bf16(oacc[dt][gq * 4 + 0] * sc);
            pk.y = f32_bf16(oacc[dt][gq * 4 + 1] * sc);
            pk.z = f32_bf16(oacc[dt][gq * 4 + 2] * sc);
            pk.w = f32_bf16(oacc[dt][gq * 4 + 3] * sc);
            *(ushort4v*)&ow[l32 * 136 + dt * 32 + gq * 8 + hh * 4] = pk;
        }
    __syncthreads();   // transpose writes visible before read-back
    int tl = lane >> 4, dcol = (lane & 15) * 8;
#pragma unroll
    for (int ch = 0; ch < 8; ch++) {
        int t_local = tl + ch * 4;
        short8 ov = *(const short8*)&ow[t_local * 136 + dcol];
        *(short8*)&Oout[((size_t)(b * T_SEQ) + t0 + wid * 32 + t_local) * NE + hd * HD + dcol] = ov;
    }
}

// ---------------- launch ----------------
extern "C" void kernel_launch(void* const* d_in, const int* in_sizes, int n_in,
                              void* d_out, int out_size, void* d_ws, size_t ws_size,
                              hipStream_t stream) {
    const float* x  = (const float*)d_in[0];
    const float* Wq = (const float*)d_in[1];
    const float* bq = (const float*)d_in[2];
    const float* Wk = (const float*)d_in[3];
    const float* bk = (const float*)d_in[4];
    const float* Wv = (const float*)d_in[5];
    const float* bv = (const float*)d_in[6];
    const float* Wo = (const float*)d_in[7];
    const float* bo = (const float*)d_in[8];
    float* out = (float*)d_out;
    char* ws = (char*)d_ws;

    // aliasing: ao reuses xh (xh dead after QKV gemm); wot reuses wqt (dead after QKV gemm)
    u16* xh   = (u16*)(ws);                      // 16 MB   [also ao]
    u16* wqt  = (u16*)(ws + 16777216);           // 8 MB    [also wot]
    u16* wkt  = (u16*)(ws + 25165824);           // 2 MB
    u16* wvt  = (u16*)(ws + 27262976);           // 2 MB
    u16* qr   = (u16*)(ws + 29360128);           // 16 MB
    u16* kr   = (u16*)(ws + 46137344);           // 4 MB
    u16* vt   = (u16*)(ws + 50331648);           // 4 MB
    float* ctab = (float*)(ws + 54525952);       // 0.5 MB
    float* stab = (float*)(ws + 55050240);       // 0.5 MB
    u16* ao  = xh;
    u16* wot = wqt;

    conv_f16<<<8192, 256, 0, stream>>>(x, xh);
    transpose_convert<true><<<dim3(64, 64), dim3(32, 8), 0, stream>>>(Wq, wqt, 2048, 2048);
    transpose_convert<true><<<dim3(16, 64), dim3(32, 8), 0, stream>>>(Wk, wkt, 2048, 512);
    transpose_convert<true><<<dim3(16, 64), dim3(32, 8), 0, stream>>>(Wv, wvt, 2048, 512);
    rope_tab<<<512, 256, 0, stream>>>(ctab, stab);

    gemm_qkv<<<dim3(768), 256, 0, stream>>>(xh, wqt, wkt, wvt, bq, bk, bv,
                                            qr, kr, vt, ctab, stab);

    // Wo transpose after QKV gemm (wqt dead), before final gemm
    transpose_convert<false><<<dim3(64, 64), dim3(32, 8), 0, stream>>>(Wo, wot, 2048, 2048);

    attn_kernel<<<dim3(16, 32), 256, 0, stream>>>(qr, kr, vt, ao);

    gemm_out<<<dim3(32, 16), 256, 0, stream>>>(ao, wot, bo, out);
}

// Round 6
// 335.040 us; speedup vs baseline: 1.0468x; 1.0468x over previous
//
#include <hip/hip_runtime.h>
#include <stdint.h>
#include <math.h>

typedef unsigned short u16;
typedef __attribute__((ext_vector_type(8))) short short8;
typedef __attribute__((ext_vector_type(8))) _Float16 half8;
typedef __attribute__((ext_vector_type(4))) float float4v;
typedef __attribute__((ext_vector_type(16))) float float16v;
typedef __attribute__((ext_vector_type(4))) u16 ushort4v;

#define T_SEQ 2048
#define NB 2
#define NE 2048
#define NH 16
#define NKV 4
#define HD 128
#define KDIM 2048

union Frag { short8 s; half8 h; };

__device__ inline u16 f32_bf16(float f) {
    union { float f; uint32_t u; } v; v.f = f;
    uint32_t u = v.u;
    return (u16)((u + 0x7fffu + ((u >> 16) & 1u)) >> 16);
}
__device__ inline u16 f32_f16(float f) {
    union { _Float16 h; u16 u; } v; v.h = (_Float16)f;
    return v.u;
}

// v_cvt_pk_bf16_f32: dst.lo = bf16(lo), dst.hi = bf16(hi)  (RNE)
__device__ inline uint32_t cvtpk_bf16(float lo, float hi) {
    uint32_t r;
    asm("v_cvt_pk_bf16_f32 %0, %1, %2" : "=v"(r) : "v"(lo), "v"(hi));
    return r;
}
// v_permlane32_swap_b32: a.lanes[32+i] <-> b.lanes[i]
// after: a = [a.lo | b.lo], b = [a.hi | b.hi]
__device__ inline void perm32swap(uint32_t& a, uint32_t& b) {
    asm("v_permlane32_swap_b32 %0, %1" : "+v"(a), "+v"(b));
}

// async global->LDS, 16B per lane; LDS dest = wave-uniform base + lane*16
typedef __attribute__((address_space(1))) const void g_void;
typedef __attribute__((address_space(3))) void l_void;
#define GLOAD16(g, l) __builtin_amdgcn_global_load_lds((g_void*)(g), (l_void*)(l), 16, 0, 0)

// ---------------- conversion kernels ----------------
__global__ void conv_f16(const float* __restrict__ in, u16* __restrict__ out) {
    int i = blockIdx.x * blockDim.x + threadIdx.x;
    float4 v = ((const float4*)in)[i];
    ushort4v o;
    o.x = f32_f16(v.x); o.y = f32_f16(v.y); o.z = f32_f16(v.z); o.w = f32_f16(v.w);
    *(ushort4v*)(out + (size_t)i * 4) = o;
}

template<bool TO_F16>
__global__ void transpose_convert(const float* __restrict__ in, u16* __restrict__ out,
                                  int K, int N) {
    __shared__ float tile[32][33];
    int n0 = blockIdx.x * 32, k0 = blockIdx.y * 32;
    int tx = threadIdx.x, ty = threadIdx.y;   // 32 x 8
    for (int i = 0; i < 32; i += 8)
        tile[ty + i][tx] = in[(size_t)(k0 + ty + i) * N + n0 + tx];
    __syncthreads();
    for (int i = 0; i < 32; i += 8) {
        float v = tile[tx][ty + i];
        out[(size_t)(n0 + ty + i) * K + k0 + tx] = TO_F16 ? f32_f16(v) : f32_bf16(v);
    }
}

__global__ void rope_tab(float* __restrict__ ctab, float* __restrict__ stab) {
    int i = blockIdx.x * blockDim.x + threadIdx.x;   // < 2048*64
    int t = i >> 6, j = i & 63;
    float freqf = (float)pow(10000.0, -(double)j / 1024.0);
    float angf = (float)t * freqf;          // fp32 rounding like np.outer
    double a = (double)angf;
    ctab[i] = (float)cos(a);
    stab[i] = (float)sin(a);
}

// ---------------- GEMM main loop: R4 template, 2x BK32 sub-tiles per barrier pair ----
// R5 lesson: runtime-indexed LDS bases (buf[cur]) made the compiler recompute
// gload_lds/ds_read addresses every iteration (VALUBusy 12->29%, net regress).
// This version keeps ALL LDS addresses compile-time static (4 named buffers)
// and simply processes 64 K-elements per barrier pair instead of 32, halving
// the number of vmcnt(0) barrier drains (the dominant stall in R4: ~300cy
// drain vs ~150cy compute per 32-K step).
#define GEMM_STAGE_DECL(Asrc, Bsrc) \
    int rin = lane >> 2, ksl = lane & 3; \
    int u0r = wid * 32; \
    const u16* Ag0 = (Asrc) + (size_t)(m0 + u0r + rin) * KDIM + ksl * 8; \
    const u16* Ag1 = (Asrc) + (size_t)(m0 + u0r + 16 + rin) * KDIM + ksl * 8; \
    const u16* Bg0 = (Bsrc) + (size_t)(n0 + u0r + rin) * KDIM + ksl * 8; \
    const u16* Bg1 = (Bsrc) + (size_t)(n0 + u0r + 16 + rin) * KDIM + ksl * 8;

#define GEMM_STAGE(Abuf, Bbuf, kk) \
    GLOAD16(Ag0 + (kk), &Abuf[u0r * 32]); \
    GLOAD16(Ag1 + (kk), &Abuf[(u0r + 16) * 32]); \
    GLOAD16(Bg0 + (kk), &Bbuf[u0r * 32]); \
    GLOAD16(Bg1 + (kk), &Bbuf[(u0r + 16) * 32]);

#define GEMM_COMPUTE(Abuf, Bbuf, F16) { \
    Frag af[4], bf[4]; \
    for (int i = 0; i < 4; i++) \
        af[i].s = *(const short8*)&Abuf[(wr * 64 + i * 16 + l16) * 32 + quad * 8]; \
    for (int j = 0; j < 4; j++) \
        bf[j].s = *(const short8*)&Bbuf[(wc * 64 + j * 16 + l16) * 32 + quad * 8]; \
    for (int i = 0; i < 4; i++) \
        for (int j = 0; j < 4; j++) { \
            if (F16) \
                acc[i][j] = __builtin_amdgcn_mfma_f32_16x16x32_f16(af[i].h, bf[j].h, acc[i][j], 0, 0, 0); \
            else \
                acc[i][j] = __builtin_amdgcn_mfma_f32_16x16x32_bf16(af[i].s, bf[j].s, acc[i][j], 0, 0, 0); \
        } \
}

#define GEMM_MAINLOOP(F16) \
    for (int k0 = 0; k0 < KDIM; k0 += 64) { \
        __syncthreads(); \
        GEMM_STAGE(Alds0, Blds0, k0) \
        GEMM_STAGE(Alds1, Blds1, k0 + 32) \
        __syncthreads(); \
        GEMM_COMPUTE(Alds0, Blds0, F16) \
        GEMM_COMPUTE(Alds1, Blds1, F16) \
    }

// ---------------- fused Q+K+V projection: 1D grid of 768 equal-cost blocks ----------------
// lin <  512: Q:  C[t,d] = xh @ wqt^T, rope -> [B,NH,T,D]
// 512..639 : K:  C[t,d] = xh @ wkt^T, rope -> [B,NKV,T,D]
// 640..767 : V^T by operand swap: A = wvt (rows d=512), Bt = xh (rows t=4096)
//            -> C[d,t], write [B,NKV,D,T] coalesced along t (avoids the 47x
//            store-side write amplification measured in R1).
__global__ __launch_bounds__(256)
void gemm_qkv(const u16* __restrict__ xh, const u16* __restrict__ wqt,
              const u16* __restrict__ wkt, const u16* __restrict__ wvt,
              const float* __restrict__ bq, const float* __restrict__ bk,
              const float* __restrict__ bv,
              u16* __restrict__ qout, u16* __restrict__ kout, u16* __restrict__ vout,
              const float* __restrict__ ctab, const float* __restrict__ stab) {
    __shared__ u16 Alds0[128 * 32], Alds1[128 * 32];
    __shared__ u16 Blds0[128 * 32], Blds1[128 * 32];
    int tid = threadIdx.x;
    int wid = tid >> 6, lane = tid & 63;
    int quad = lane >> 4, l16 = lane & 15;
    int wr = wid >> 1, wc = wid & 1;

    int lin = blockIdx.x;
    int mode, m0, n0;
    const u16 *A, *Bt;
    if (lin < 512) {          // Q
        mode = 0; m0 = (lin >> 4) * 128; n0 = (lin & 15) * 128; A = xh; Bt = wqt;
    } else if (lin < 640) {   // K
        int i = lin - 512;
        mode = 1; m0 = (i >> 2) * 128; n0 = (i & 3) * 128; A = xh; Bt = wkt;
    } else {                  // V (swapped)
        int i = lin - 640;
        mode = 2; m0 = (i & 3) * 128; n0 = (i >> 2) * 128; A = wvt; Bt = xh;
    }

    float4v acc[4][4];
    for (int i = 0; i < 4; i++) for (int j = 0; j < 4; j++) acc[i][j] = (float4v){0,0,0,0};

    GEMM_STAGE_DECL(A, Bt)
    GEMM_MAINLOOP(true)

    if (mode == 2) {
        // rows m = global d (h = m>>7, d = m&127); cols = global t (b = col>>11)
        for (int i = 0; i < 4; i++) {
            int mbase = m0 + wr * 64 + i * 16 + quad * 4;
            float brow[4];
            for (int r = 0; r < 4; r++) brow[r] = bv[mbase + r];
            for (int j = 0; j < 4; j++) {
                int col = n0 + wc * 64 + j * 16 + l16;
                int b = col >> 11, t = col & 2047;
                for (int r = 0; r < 4; r++) {
                    int m = mbase + r;
                    float val = acc[i][j][r] + brow[r];
                    vout[(((size_t)(b * NKV + (m >> 7))) * HD + (m & 127)) * T_SEQ + t] = f32_bf16(val);
                }
            }
        }
    } else {
        const float* bias = mode ? bk : bq;
        u16* outU = mode ? kout : qout;
        int nheads = mode ? NKV : NH;
        for (int i = 0; i < 4; i++) {
            int mbase = m0 + wr * 64 + i * 16 + quad * 4;
            for (int j = 0; j < 4; j++) {
                int col = n0 + wc * 64 + j * 16 + l16;
                float bcol = bias[col];
                for (int r = 0; r < 4; r++) {
                    int m = mbase + r;
                    float val = acc[i][j][r] + bcol;
                    int b = m >> 11, t = m & 2047;
                    int h = col >> 7, d = col & 127;
                    int jj = d >> 1;
                    float c = ctab[t * 64 + jj];
                    float s = stab[t * 64 + jj];
                    float partner = __shfl_xor(val, 1, 64);
                    float o = (d & 1) ? (partner * s + val * c) : (val * c - partner * s);
                    outU[(((size_t)(b * nheads + h)) * T_SEQ + t) * HD + d] = f32_bf16(o);
                }
            }
        }
    }
}

// ---------------- output projection GEMM (bf16 in, fp32 + bias out) ----------------
__global__ __launch_bounds__(256)
void gemm_out(const u16* __restrict__ A, const u16* __restrict__ Bt,
              const float* __restrict__ bias, float* __restrict__ outF) {
    __shared__ u16 Alds0[128 * 32], Alds1[128 * 32];
    __shared__ u16 Blds0[128 * 32], Blds1[128 * 32];
    int tid = threadIdx.x;
    int wid = tid >> 6, lane = tid & 63;
    int quad = lane >> 4, l16 = lane & 15;
    int wr = wid >> 1, wc = wid & 1;
    int m0 = blockIdx.x * 128, n0 = blockIdx.y * 128;

    float4v acc[4][4];
    for (int i = 0; i < 4; i++) for (int j = 0; j < 4; j++) acc[i][j] = (float4v){0,0,0,0};

    GEMM_STAGE_DECL(A, Bt)
    GEMM_MAINLOOP(false)

    for (int i = 0; i < 4; i++) {
        int mbase = m0 + wr * 64 + i * 16 + quad * 4;
        for (int j = 0; j < 4; j++) {
            int col = n0 + wc * 64 + j * 16 + l16;
            float bcol = bias[col];
            for (int r = 0; r < 4; r++)
                outF[(size_t)(mbase + r) * NE + col] = acc[i][j][r] + bcol;
        }
    }
}

// ---------------- flash attention v4 ----------------
// v3h + (T12) in-register P via cvt_pk+permlane32_swap (plds removed: -18.4KB
// LDS, -1 barrier/tile), (T13) defer-max THR=8, (T5) setprio around MFMA
// clusters, fully-masked diagonal-tile skip for waves 0,1.
__global__ __launch_bounds__(256, 2)
void attn_kernel(const u16* __restrict__ Qr, const u16* __restrict__ Kr,
                 const u16* __restrict__ Vt, u16* __restrict__ Oout) {
    __shared__ u16 smem[17920];            // 35840 B
    u16* klds = smem;                      // K tile [s=64][d=128] stride 136
    u16* vlds = smem + 8704;               // V^T tile [d=128][s=64] stride 72
    int tid = threadIdx.x;
    int wid = tid >> 6, lane = tid & 63;
    int l32 = lane & 31, hh = lane >> 5;

    int lin = blockIdx.x + (blockIdx.y << 4);
    int g = lin >> 5, bh = lin & 31;
    int qt = (lin < 256) ? (15 - g) : (g - 8);   // balance: CU gets qt and 15-qt
    int b = bh >> 4, hd = bh & 15, kvh = hd >> 2;
    int t0 = qt * 128;

    const u16* Qb = Qr + (((size_t)(b * NH + hd)) * T_SEQ + t0 + wid * 32) * HD;
    const u16* Kb = Kr + ((size_t)(b * NKV + kvh)) * T_SEQ * HD;
    const u16* Vb = Vt + ((size_t)(b * NKV + kvh)) * HD * T_SEQ;

    // Q as B-operand frags: col = t = l32, k = d
    short8 qf[8];
#pragma unroll
    for (int ks = 0; ks < 8; ks++)
        qf[ks] = *(const short8*)(Qb + (size_t)l32 * HD + ks * 16 + hh * 8);

    float16v oacc[4];   // O^T: rows d (dt*32 block), cols t (= l32)
#pragma unroll
    for (int dt = 0; dt < 4; dt++)
        oacc[dt] = (float16v){0,0,0,0,0,0,0,0,0,0,0,0,0,0,0,0};
    float m_run = -INFINITY, l_run = 0.f;

    int ksr = tid >> 2, kc = (tid & 3) * 32;   // K staging: row s, col base (u16)
    int vdr = tid >> 1, vc = (tid & 1) * 32;   // V staging: row d, col base (u16)

    int nst = 2 * qt + 2;

    {   // prologue: stage tile 0
        const u16* ksrc = Kb + (size_t)ksr * HD + kc;
        const u16* vsrc = Vb + (size_t)vdr * T_SEQ + vc;
        short8 kr0[4], vr0[4];
#pragma unroll
        for (int i = 0; i < 4; i++) kr0[i] = *(const short8*)(ksrc + i * 8);
#pragma unroll
        for (int i = 0; i < 4; i++) vr0[i] = *(const short8*)(vsrc + i * 8);
#pragma unroll
        for (int i = 0; i < 4; i++) *(short8*)&klds[ksr * 136 + kc + i * 8] = kr0[i];
#pragma unroll
        for (int i = 0; i < 4; i++) *(short8*)&vlds[vdr * 72 + vc + i * 8] = vr0[i];
    }
    __syncthreads();

    for (int st = 0; st < nst; st++) {
        short8 krg[4], vrg[4];
        bool more = (st + 1 < nst);
        if (more) {   // prefetch next K/V tile into registers
            const u16* ksrc = Kb + ((size_t)(st + 1) * 64 + ksr) * HD + kc;
            const u16* vsrc = Vb + (size_t)vdr * T_SEQ + (st + 1) * 64 + vc;
#pragma unroll
            for (int i = 0; i < 4; i++) krg[i] = *(const short8*)(ksrc + i * 8);
#pragma unroll
            for (int i = 0; i < 4; i++) vrg[i] = *(const short8*)(vsrc + i * 8);
        }

        // wave-uniform skip: tile entirely above this wave's causal diagonal
        // (only st == 2qt+1 for waves 0,1). Barriers stay outside.
        bool active = (st * 64) <= (t0 + wid * 32 + 31);
        if (active) {
            // S^T = K * Q^T : rows = s (2 tiles of 32), cols = t (32)
            float16v sfa[2];
            sfa[0] = (float16v){0,0,0,0,0,0,0,0,0,0,0,0,0,0,0,0};
            sfa[1] = (float16v){0,0,0,0,0,0,0,0,0,0,0,0,0,0,0,0};
            __builtin_amdgcn_s_setprio(1);
#pragma unroll
            for (int ks = 0; ks < 8; ks++) {
                short8 kf0 = *(const short8*)&klds[l32 * 136 + ks * 16 + hh * 8];
                short8 kf1 = *(const short8*)&klds[(32 + l32) * 136 + ks * 16 + hh * 8];
                sfa[0] = __builtin_amdgcn_mfma_f32_32x32x16_bf16(kf0, qf[ks], sfa[0], 0, 0, 0);
                sfa[1] = __builtin_amdgcn_mfma_f32_32x32x16_bf16(kf1, qf[ks], sfa[1], 0, 0, 0);
            }
            __builtin_amdgcn_s_setprio(0);

            int tg = t0 + wid * 32 + l32;
            if (st >= 2 * qt) {   // causal mask on diagonal tiles
#pragma unroll
                for (int stile = 0; stile < 2; stile++)
#pragma unroll
                    for (int r = 0; r < 16; r++) {
                        int s = st * 64 + stile * 32 + (r & 3) + 8 * (r >> 2) + 4 * hh;
                        if (s > tg) sfa[stile][r] = -INFINITY;
                    }
            }

            // online softmax over s; T13 defer-max: skip O-rescale while the
            // tile max stays within 8 of the running max (P bounded by e^8).
            float mx = -INFINITY;
#pragma unroll
            for (int stile = 0; stile < 2; stile++)
#pragma unroll
                for (int r = 0; r < 16; r++) mx = fmaxf(mx, sfa[stile][r]);
            mx = fmaxf(mx, __shfl_xor(mx, 32, 64));
            bool nos = __all(mx - m_run <= 8.f);   // wave-uniform
            float mnew = nos ? m_run : fmaxf(m_run, mx);
            float alpha = nos ? 1.f : __expf(m_run - mnew);
            float psum = 0.f;
#pragma unroll
            for (int stile = 0; stile < 2; stile++)
#pragma unroll
                for (int r = 0; r < 16; r++) {
                    float p = __expf(sfa[stile][r] - mnew);
                    sfa[stile][r] = p;
                    psum += p;
                }
            psum += __shfl_xor(psum, 32, 64);
            l_run = l_run * alpha + psum;
            m_run = mnew;

            if (!nos) {
#pragma unroll
                for (int dt = 0; dt < 4; dt++)
#pragma unroll
                    for (int r = 0; r < 16; r++) oacc[dt][r] *= alpha;
            }

            // T12: P^T -> B-operand fragments entirely in registers.
            // Accumulator holds s_local=(r&3)+8(r>>2)+4hh; the B-operand needs
            // k=s=hh*8+e per 16-block. swap(P0,P2)/(P1,P3) redistributes the
            // 4-element groups across the lane halves: after swap,
            // P0=[lo|lo'], P2=[hi|hi'] which is exactly word0/word2 for both hh.
            __builtin_amdgcn_s_setprio(1);
#pragma unroll
            for (int g2 = 0; g2 < 4; g2++) {           // s16-block = ks2
                int stile = g2 >> 1, gg = g2 & 1;
                uint32_t P0 = cvtpk_bf16(sfa[stile][8 * gg + 0], sfa[stile][8 * gg + 1]);
                uint32_t P1 = cvtpk_bf16(sfa[stile][8 * gg + 2], sfa[stile][8 * gg + 3]);
                uint32_t P2 = cvtpk_bf16(sfa[stile][8 * gg + 4], sfa[stile][8 * gg + 5]);
                uint32_t P3 = cvtpk_bf16(sfa[stile][8 * gg + 6], sfa[stile][8 * gg + 7]);
                perm32swap(P0, P2);
                perm32swap(P1, P3);
                union { uint32_t w[4]; short8 s; } pf;
                pf.w[0] = P0; pf.w[1] = P1; pf.w[2] = P2; pf.w[3] = P3;
#pragma unroll
                for (int dt = 0; dt < 4; dt++) {
                    short8 vf = *(const short8*)&vlds[(dt * 32 + l32) * 72 + g2 * 16 + hh * 8];
                    oacc[dt] = __builtin_amdgcn_mfma_f32_32x32x16_bf16(vf, pf.s, oacc[dt], 0, 0, 0);
                }
            }
            __builtin_amdgcn_s_setprio(0);
        }

        __syncthreads();   // all K/V reads done before overwrite
        if (more) {
#pragma unroll
            for (int i = 0; i < 4; i++) *(short8*)&klds[ksr * 136 + kc + i * 8] = krg[i];
#pragma unroll
            for (int i = 0; i < 4; i++) *(short8*)&vlds[vdr * 72 + vc + i * 8] = vrg[i];
        }
        __syncthreads();   // staging visible before next iteration's reads
    }

    // epilogue: scale (per-lane), transpose O^T -> O via LDS scratch
    const float scale = 0.022097086912079608f;   // 2048^-0.5
    float sc = scale / l_run;
    u16* ow = smem + wid * 4352;           // [t=32][d=128] stride 136
#pragma unroll
    for (int dt = 0; dt < 4; dt++)
#pragma unroll
        for (int gq = 0; gq < 4; gq++) {
            ushort4v pk;
            pk.x = f32_bf16(oacc[dt][gq * 4 + 0] * sc);
            pk.y = f32_bf16(oacc[dt][gq * 4 + 1] * sc);
            pk.z = f32_bf16(oacc[dt][gq * 4 + 2] * sc);
            pk.w = f32_bf16(oacc[dt][gq * 4 + 3] * sc);
            *(ushort4v*)&ow[l32 * 136 + dt * 32 + gq * 8 + hh * 4] = pk;
        }
    __syncthreads();   // transpose writes visible before read-back
    int tl = lane >> 4, dcol = (lane & 15) * 8;
#pragma unroll
    for (int ch = 0; ch < 8; ch++) {
        int t_local = tl + ch * 4;
        short8 ov = *(const short8*)&ow[t_local * 136 + dcol];
        *(short8*)&Oout[((size_t)(b * T_SEQ) + t0 + wid * 32 + t_local) * NE + hd * HD + dcol] = ov;
    }
}

// ---------------- launch ----------------
extern "C" void kernel_launch(void* const* d_in, const int* in_sizes, int n_in,
                              void* d_out, int out_size, void* d_ws, size_t ws_size,
                              hipStream_t stream) {
    const float* x  = (const float*)d_in[0];
    const float* Wq = (const float*)d_in[1];
    const float* bq = (const float*)d_in[2];
    const float* Wk = (const float*)d_in[3];
    const float* bk = (const float*)d_in[4];
    const float* Wv = (const float*)d_in[5];
    const float* bv = (const float*)d_in[6];
    const float* Wo = (const float*)d_in[7];
    const float* bo = (const float*)d_in[8];
    float* out = (float*)d_out;
    char* ws = (char*)d_ws;

    // aliasing: ao reuses xh (xh dead after QKV gemm); wot reuses wqt (dead after QKV gemm)
    u16* xh   = (u16*)(ws);                      // 16 MB   [also ao]
    u16* wqt  = (u16*)(ws + 16777216);           // 8 MB    [also wot]
    u16* wkt  = (u16*)(ws + 25165824);           // 2 MB
    u16* wvt  = (u16*)(ws + 27262976);           // 2 MB
    u16* qr   = (u16*)(ws + 29360128);           // 16 MB
    u16* kr   = (u16*)(ws + 46137344);           // 4 MB
    u16* vt   = (u16*)(ws + 50331648);           // 4 MB
    float* ctab = (float*)(ws + 54525952);       // 0.5 MB
    float* stab = (float*)(ws + 55050240);       // 0.5 MB
    u16* ao  = xh;
    u16* wot = wqt;

    conv_f16<<<8192, 256, 0, stream>>>(x, xh);
    transpose_convert<true><<<dim3(64, 64), dim3(32, 8), 0, stream>>>(Wq, wqt, 2048, 2048);
    transpose_convert<true><<<dim3(16, 64), dim3(32, 8), 0, stream>>>(Wk, wkt, 2048, 512);
    transpose_convert<true><<<dim3(16, 64), dim3(32, 8), 0, stream>>>(Wv, wvt, 2048, 512);
    rope_tab<<<512, 256, 0, stream>>>(ctab, stab);

    gemm_qkv<<<dim3(768), 256, 0, stream>>>(xh, wqt, wkt, wvt, bq, bk, bv,
                                            qr, kr, vt, ctab, stab);

    // Wo transpose after QKV gemm (wqt dead), before final gemm
    transpose_convert<false><<<dim3(64, 64), dim3(32, 8), 0, stream>>>(Wo, wot, 2048, 2048);

    attn_kernel<<<dim3(16, 32), 256, 0, stream>>>(qr, kr, vt, ao);

    gemm_out<<<dim3(32, 16), 256, 0, stream>>>(ao, wot, bo, out);
}

// Round 8
// 330.330 us; speedup vs baseline: 1.0617x; 1.0143x over previous
//
#include <hip/hip_runtime.h>
#include <stdint.h>
#include <math.h>

typedef unsigned short u16;
typedef __attribute__((ext_vector_type(8))) short short8;
typedef __attribute__((ext_vector_type(8))) _Float16 half8;
typedef __attribute__((ext_vector_type(4))) float float4v;
typedef __attribute__((ext_vector_type(16))) float float16v;
typedef __attribute__((ext_vector_type(4))) u16 ushort4v;

#define T_SEQ 2048
#define NB 2
#define NE 2048
#define NH 16
#define NKV 4
#define HD 128
#define KDIM 2048

union Frag { short8 s; half8 h; };

__device__ inline u16 f32_bf16(float f) {
    union { float f; uint32_t u; } v; v.f = f;
    uint32_t u = v.u;
    return (u16)((u + 0x7fffu + ((u >> 16) & 1u)) >> 16);
}
__device__ inline u16 f32_f16(float f) {
    union { _Float16 h; u16 u; } v; v.h = (_Float16)f;
    return v.u;
}

// v_cvt_pk_bf16_f32: dst.lo = bf16(lo), dst.hi = bf16(hi)  (RNE)
__device__ inline uint32_t cvtpk_bf16(float lo, float hi) {
    uint32_t r;
    asm("v_cvt_pk_bf16_f32 %0, %1, %2" : "=v"(r) : "v"(lo), "v"(hi));
    return r;
}
// v_permlane32_swap_b32: a.lanes[32+i] <-> b.lanes[i]
// after: a = [a.lo | b.lo], b = [a.hi | b.hi]
__device__ inline void perm32swap(uint32_t& a, uint32_t& b) {
    asm("v_permlane32_swap_b32 %0, %1" : "+v"(a), "+v"(b));
}

// async global->LDS, 16B per lane; LDS dest = wave-uniform base + lane*16
typedef __attribute__((address_space(1))) const void g_void;
typedef __attribute__((address_space(3))) void l_void;
#define GLOAD16(g, l) __builtin_amdgcn_global_load_lds((g_void*)(g), (l_void*)(l), 16, 0, 0)

// ---------------- conversion kernels ----------------
__global__ void conv_f16(const float* __restrict__ in, u16* __restrict__ out) {
    int i = blockIdx.x * blockDim.x + threadIdx.x;
    float4 v = ((const float4*)in)[i];
    ushort4v o;
    o.x = f32_f16(v.x); o.y = f32_f16(v.y); o.z = f32_f16(v.z); o.w = f32_f16(v.w);
    *(ushort4v*)(out + (size_t)i * 4) = o;
}

template<bool TO_F16>
__global__ void transpose_convert(const float* __restrict__ in, u16* __restrict__ out,
                                  int K, int N) {
    __shared__ float tile[32][33];
    int n0 = blockIdx.x * 32, k0 = blockIdx.y * 32;
    int tx = threadIdx.x, ty = threadIdx.y;   // 32 x 8
    for (int i = 0; i < 32; i += 8)
        tile[ty + i][tx] = in[(size_t)(k0 + ty + i) * N + n0 + tx];
    __syncthreads();
    for (int i = 0; i < 32; i += 8) {
        float v = tile[tx][ty + i];
        out[(size_t)(n0 + ty + i) * K + k0 + tx] = TO_F16 ? f32_f16(v) : f32_bf16(v);
    }
}

__global__ void rope_tab(float* __restrict__ ctab, float* __restrict__ stab) {
    int i = blockIdx.x * blockDim.x + threadIdx.x;   // < 2048*64
    int t = i >> 6, j = i & 63;
    float freqf = (float)pow(10000.0, -(double)j / 1024.0);
    float angf = (float)t * freqf;          // fp32 rounding like np.outer
    double a = (double)angf;
    ctab[i] = (float)cos(a);
    stab[i] = (float)sin(a);
}

// ---------------- GEMM main loop: T3 2-phase pipeline, static buffers ----------------
// R5 lesson: this schedule with runtime buf[cur] indexing regressed (rule #20,
// VALUBusy 12->29%). R6 lesson: stage->drain->compute exposes full load
// latency (MfmaUtil 22%). This version = R5's schedule + R6's static naming:
// issue next sub-tile's global_load_lds BEFORE computing the current one, so
// the barrier's implicit vmcnt(0) waits on loads that had the whole MFMA
// phase (~250cy) to complete. 2-phase unroll keeps every LDS address
// compile-time constant. Race-safe: each buffer's stage is separated from
// its previous readers by exactly one barrier; each compute from its staging
// by a barrier whose vmcnt(0) drain completes the LDS-DMA writes.
#define GEMM_STAGE_DECL(Asrc, Bsrc) \
    int rin = lane >> 2, ksl = lane & 3; \
    int u0r = wid * 32; \
    const u16* Ag0 = (Asrc) + (size_t)(m0 + u0r + rin) * KDIM + ksl * 8; \
    const u16* Ag1 = (Asrc) + (size_t)(m0 + u0r + 16 + rin) * KDIM + ksl * 8; \
    const u16* Bg0 = (Bsrc) + (size_t)(n0 + u0r + rin) * KDIM + ksl * 8; \
    const u16* Bg1 = (Bsrc) + (size_t)(n0 + u0r + 16 + rin) * KDIM + ksl * 8;

#define GEMM_STAGE(Abuf, Bbuf, kk) \
    GLOAD16(Ag0 + (kk), &Abuf[u0r * 32]); \
    GLOAD16(Ag1 + (kk), &Abuf[(u0r + 16) * 32]); \
    GLOAD16(Bg0 + (kk), &Bbuf[u0r * 32]); \
    GLOAD16(Bg1 + (kk), &Bbuf[(u0r + 16) * 32]);

#define GEMM_COMPUTE(Abuf, Bbuf, F16) { \
    Frag af[4], bf[4]; \
    for (int i = 0; i < 4; i++) \
        af[i].s = *(const short8*)&Abuf[(wr * 64 + i * 16 + l16) * 32 + quad * 8]; \
    for (int j = 0; j < 4; j++) \
        bf[j].s = *(const short8*)&Bbuf[(wc * 64 + j * 16 + l16) * 32 + quad * 8]; \
    for (int i = 0; i < 4; i++) \
        for (int j = 0; j < 4; j++) { \
            if (F16) \
                acc[i][j] = __builtin_amdgcn_mfma_f32_16x16x32_f16(af[i].h, bf[j].h, acc[i][j], 0, 0, 0); \
            else \
                acc[i][j] = __builtin_amdgcn_mfma_f32_16x16x32_bf16(af[i].s, bf[j].s, acc[i][j], 0, 0, 0); \
        } \
}

#define GEMM_MAINLOOP(F16) \
    GEMM_STAGE(Alds0, Blds0, 0) \
    __syncthreads(); \
    for (int k0 = 0; k0 < KDIM; k0 += 64) { \
        GEMM_STAGE(Alds1, Blds1, k0 + 32) \
        GEMM_COMPUTE(Alds0, Blds0, F16) \
        __syncthreads(); \
        if (k0 + 64 < KDIM) { GEMM_STAGE(Alds0, Blds0, k0 + 64) } \
        GEMM_COMPUTE(Alds1, Blds1, F16) \
        __syncthreads(); \
    }

// ---------------- fused Q+K+V projection: 1D grid of 768 equal-cost blocks ----------------
// lin <  512: Q:  C[t,d] = xh @ wqt^T, rope -> [B,NH,T,D]
// 512..639 : K:  C[t,d] = xh @ wkt^T, rope -> [B,NKV,T,D]
// 640..767 : V^T by operand swap: A = wvt (rows d=512), Bt = xh (rows t=4096)
//            -> C[d,t], write [B,NKV,D,T] coalesced along t (avoids the 47x
//            store-side write amplification measured in R1).
__global__ __launch_bounds__(256)
void gemm_qkv(const u16* __restrict__ xh, const u16* __restrict__ wqt,
              const u16* __restrict__ wkt, const u16* __restrict__ wvt,
              const float* __restrict__ bq, const float* __restrict__ bk,
              const float* __restrict__ bv,
              u16* __restrict__ qout, u16* __restrict__ kout, u16* __restrict__ vout,
              const float* __restrict__ ctab, const float* __restrict__ stab) {
    __shared__ u16 Alds0[128 * 32], Alds1[128 * 32];
    __shared__ u16 Blds0[128 * 32], Blds1[128 * 32];
    int tid = threadIdx.x;
    int wid = tid >> 6, lane = tid & 63;
    int quad = lane >> 4, l16 = lane & 15;
    int wr = wid >> 1, wc = wid & 1;

    int lin = blockIdx.x;
    int mode, m0, n0;
    const u16 *A, *Bt;
    if (lin < 512) {          // Q
        mode = 0; m0 = (lin >> 4) * 128; n0 = (lin & 15) * 128; A = xh; Bt = wqt;
    } else if (lin < 640) {   // K
        int i = lin - 512;
        mode = 1; m0 = (i >> 2) * 128; n0 = (i & 3) * 128; A = xh; Bt = wkt;
    } else {                  // V (swapped)
        int i = lin - 640;
        mode = 2; m0 = (i & 3) * 128; n0 = (i >> 2) * 128; A = wvt; Bt = xh;
    }

    float4v acc[4][4];
    for (int i = 0; i < 4; i++) for (int j = 0; j < 4; j++) acc[i][j] = (float4v){0,0,0,0};

    GEMM_STAGE_DECL(A, Bt)
    GEMM_MAINLOOP(true)

    if (mode == 2) {
        // rows m = global d (h = m>>7, d = m&127); cols = global t (b = col>>11)
        for (int i = 0; i < 4; i++) {
            int mbase = m0 + wr * 64 + i * 16 + quad * 4;
            float brow[4];
            for (int r = 0; r < 4; r++) brow[r] = bv[mbase + r];
            for (int j = 0; j < 4; j++) {
                int col = n0 + wc * 64 + j * 16 + l16;
                int b = col >> 11, t = col & 2047;
                for (int r = 0; r < 4; r++) {
                    int m = mbase + r;
                    float val = acc[i][j][r] + brow[r];
                    vout[(((size_t)(b * NKV + (m >> 7))) * HD + (m & 127)) * T_SEQ + t] = f32_bf16(val);
                }
            }
        }
    } else {
        const float* bias = mode ? bk : bq;
        u16* outU = mode ? kout : qout;
        int nheads = mode ? NKV : NH;
        for (int i = 0; i < 4; i++) {
            int mbase = m0 + wr * 64 + i * 16 + quad * 4;
            for (int j = 0; j < 4; j++) {
                int col = n0 + wc * 64 + j * 16 + l16;
                float bcol = bias[col];
                for (int r = 0; r < 4; r++) {
                    int m = mbase + r;
                    float val = acc[i][j][r] + bcol;
                    int b = m >> 11, t = m & 2047;
                    int h = col >> 7, d = col & 127;
                    int jj = d >> 1;
                    float c = ctab[t * 64 + jj];
                    float s = stab[t * 64 + jj];
                    float partner = __shfl_xor(val, 1, 64);
                    float o = (d & 1) ? (partner * s + val * c) : (val * c - partner * s);
                    outU[(((size_t)(b * nheads + h)) * T_SEQ + t) * HD + d] = f32_bf16(o);
                }
            }
        }
    }
}

// ---------------- output projection GEMM (bf16 in, fp32 + bias out) ----------------
__global__ __launch_bounds__(256)
void gemm_out(const u16* __restrict__ A, const u16* __restrict__ Bt,
              const float* __restrict__ bias, float* __restrict__ outF) {
    __shared__ u16 Alds0[128 * 32], Alds1[128 * 32];
    __shared__ u16 Blds0[128 * 32], Blds1[128 * 32];
    int tid = threadIdx.x;
    int wid = tid >> 6, lane = tid & 63;
    int quad = lane >> 4, l16 = lane & 15;
    int wr = wid >> 1, wc = wid & 1;
    int m0 = blockIdx.x * 128, n0 = blockIdx.y * 128;

    float4v acc[4][4];
    for (int i = 0; i < 4; i++) for (int j = 0; j < 4; j++) acc[i][j] = (float4v){0,0,0,0};

    GEMM_STAGE_DECL(A, Bt)
    GEMM_MAINLOOP(false)

    for (int i = 0; i < 4; i++) {
        int mbase = m0 + wr * 64 + i * 16 + quad * 4;
        for (int j = 0; j < 4; j++) {
            int col = n0 + wc * 64 + j * 16 + l16;
            float bcol = bias[col];
            for (int r = 0; r < 4; r++)
                outF[(size_t)(mbase + r) * NE + col] = acc[i][j][r] + bcol;
        }
    }
}

// ---------------- flash attention v4 ----------------
// v3h + (T12) in-register P via cvt_pk+permlane32_swap (plds removed: -18.4KB
// LDS, -1 barrier/tile), (T13) defer-max THR=8, (T5) setprio around MFMA
// clusters, fully-masked diagonal-tile skip for waves 0,1.
__global__ __launch_bounds__(256, 2)
void attn_kernel(const u16* __restrict__ Qr, const u16* __restrict__ Kr,
                 const u16* __restrict__ Vt, u16* __restrict__ Oout) {
    __shared__ u16 smem[17920];            // 35840 B
    u16* klds = smem;                      // K tile [s=64][d=128] stride 136
    u16* vlds = smem + 8704;               // V^T tile [d=128][s=64] stride 72
    int tid = threadIdx.x;
    int wid = tid >> 6, lane = tid & 63;
    int l32 = lane & 31, hh = lane >> 5;

    int lin = blockIdx.x + (blockIdx.y << 4);
    int g = lin >> 5, bh = lin & 31;
    int qt = (lin < 256) ? (15 - g) : (g - 8);   // balance: CU gets qt and 15-qt
    int b = bh >> 4, hd = bh & 15, kvh = hd >> 2;
    int t0 = qt * 128;

    const u16* Qb = Qr + (((size_t)(b * NH + hd)) * T_SEQ + t0 + wid * 32) * HD;
    const u16* Kb = Kr + ((size_t)(b * NKV + kvh)) * T_SEQ * HD;
    const u16* Vb = Vt + ((size_t)(b * NKV + kvh)) * HD * T_SEQ;

    // Q as B-operand frags: col = t = l32, k = d
    short8 qf[8];
#pragma unroll
    for (int ks = 0; ks < 8; ks++)
        qf[ks] = *(const short8*)(Qb + (size_t)l32 * HD + ks * 16 + hh * 8);

    float16v oacc[4];   // O^T: rows d (dt*32 block), cols t (= l32)
#pragma unroll
    for (int dt = 0; dt < 4; dt++)
        oacc[dt] = (float16v){0,0,0,0,0,0,0,0,0,0,0,0,0,0,0,0};
    float m_run = -INFINITY, l_run = 0.f;

    int ksr = tid >> 2, kc = (tid & 3) * 32;   // K staging: row s, col base (u16)
    int vdr = tid >> 1, vc = (tid & 1) * 32;   // V staging: row d, col base (u16)

    int nst = 2 * qt + 2;

    {   // prologue: stage tile 0
        const u16* ksrc = Kb + (size_t)ksr * HD + kc;
        const u16* vsrc = Vb + (size_t)vdr * T_SEQ + vc;
        short8 kr0[4], vr0[4];
#pragma unroll
        for (int i = 0; i < 4; i++) kr0[i] = *(const short8*)(ksrc + i * 8);
#pragma unroll
        for (int i = 0; i < 4; i++) vr0[i] = *(const short8*)(vsrc + i * 8);
#pragma unroll
        for (int i = 0; i < 4; i++) *(short8*)&klds[ksr * 136 + kc + i * 8] = kr0[i];
#pragma unroll
        for (int i = 0; i < 4; i++) *(short8*)&vlds[vdr * 72 + vc + i * 8] = vr0[i];
    }
    __syncthreads();

    for (int st = 0; st < nst; st++) {
        short8 krg[4], vrg[4];
        bool more = (st + 1 < nst);
        if (more) {   // prefetch next K/V tile into registers
            const u16* ksrc = Kb + ((size_t)(st + 1) * 64 + ksr) * HD + kc;
            const u16* vsrc = Vb + (size_t)vdr * T_SEQ + (st + 1) * 64 + vc;
#pragma unroll
            for (int i = 0; i < 4; i++) krg[i] = *(const short8*)(ksrc + i * 8);
#pragma unroll
            for (int i = 0; i < 4; i++) vrg[i] = *(const short8*)(vsrc + i * 8);
        }

        // wave-uniform skip: tile entirely above this wave's causal diagonal
        // (only st == 2qt+1 for waves 0,1). Barriers stay outside.
        bool active = (st * 64) <= (t0 + wid * 32 + 31);
        if (active) {
            // S^T = K * Q^T : rows = s (2 tiles of 32), cols = t (32)
            float16v sfa[2];
            sfa[0] = (float16v){0,0,0,0,0,0,0,0,0,0,0,0,0,0,0,0};
            sfa[1] = (float16v){0,0,0,0,0,0,0,0,0,0,0,0,0,0,0,0};
            __builtin_amdgcn_s_setprio(1);
#pragma unroll
            for (int ks = 0; ks < 8; ks++) {
                short8 kf0 = *(const short8*)&klds[l32 * 136 + ks * 16 + hh * 8];
                short8 kf1 = *(const short8*)&klds[(32 + l32) * 136 + ks * 16 + hh * 8];
                sfa[0] = __builtin_amdgcn_mfma_f32_32x32x16_bf16(kf0, qf[ks], sfa[0], 0, 0, 0);
                sfa[1] = __builtin_amdgcn_mfma_f32_32x32x16_bf16(kf1, qf[ks], sfa[1], 0, 0, 0);
            }
            __builtin_amdgcn_s_setprio(0);

            int tg = t0 + wid * 32 + l32;
            if (st >= 2 * qt) {   // causal mask on diagonal tiles
#pragma unroll
                for (int stile = 0; stile < 2; stile++)
#pragma unroll
                    for (int r = 0; r < 16; r++) {
                        int s = st * 64 + stile * 32 + (r & 3) + 8 * (r >> 2) + 4 * hh;
                        if (s > tg) sfa[stile][r] = -INFINITY;
                    }
            }

            // online softmax over s; T13 defer-max: skip O-rescale while the
            // tile max stays within 8 of the running max (P bounded by e^8).
            float mx = -INFINITY;
#pragma unroll
            for (int stile = 0; stile < 2; stile++)
#pragma unroll
                for (int r = 0; r < 16; r++) mx = fmaxf(mx, sfa[stile][r]);
            mx = fmaxf(mx, __shfl_xor(mx, 32, 64));
            bool nos = __all(mx - m_run <= 8.f);   // wave-uniform
            float mnew = nos ? m_run : fmaxf(m_run, mx);
            float alpha = nos ? 1.f : __expf(m_run - mnew);
            float psum = 0.f;
#pragma unroll
            for (int stile = 0; stile < 2; stile++)
#pragma unroll
                for (int r = 0; r < 16; r++) {
                    float p = __expf(sfa[stile][r] - mnew);
                    sfa[stile][r] = p;
                    psum += p;
                }
            psum += __shfl_xor(psum, 32, 64);
            l_run = l_run * alpha + psum;
            m_run = mnew;

            if (!nos) {
#pragma unroll
                for (int dt = 0; dt < 4; dt++)
#pragma unroll
                    for (int r = 0; r < 16; r++) oacc[dt][r] *= alpha;
            }

            // T12: P^T -> B-operand fragments entirely in registers.
            // Accumulator holds s_local=(r&3)+8(r>>2)+4hh; the B-operand needs
            // k=s=hh*8+e per 16-block. swap(P0,P2)/(P1,P3) redistributes the
            // 4-element groups across the lane halves: after swap,
            // P0=[lo|lo'], P2=[hi|hi'] which is exactly word0/word2 for both hh.
            __builtin_amdgcn_s_setprio(1);
#pragma unroll
            for (int g2 = 0; g2 < 4; g2++) {           // s16-block = ks2
                int stile = g2 >> 1, gg = g2 & 1;
                uint32_t P0 = cvtpk_bf16(sfa[stile][8 * gg + 0], sfa[stile][8 * gg + 1]);
                uint32_t P1 = cvtpk_bf16(sfa[stile][8 * gg + 2], sfa[stile][8 * gg + 3]);
                uint32_t P2 = cvtpk_bf16(sfa[stile][8 * gg + 4], sfa[stile][8 * gg + 5]);
                uint32_t P3 = cvtpk_bf16(sfa[stile][8 * gg + 6], sfa[stile][8 * gg + 7]);
                perm32swap(P0, P2);
                perm32swap(P1, P3);
                union { uint32_t w[4]; short8 s; } pf;
                pf.w[0] = P0; pf.w[1] = P1; pf.w[2] = P2; pf.w[3] = P3;
#pragma unroll
                for (int dt = 0; dt < 4; dt++) {
                    short8 vf = *(const short8*)&vlds[(dt * 32 + l32) * 72 + g2 * 16 + hh * 8];
                    oacc[dt] = __builtin_amdgcn_mfma_f32_32x32x16_bf16(vf, pf.s, oacc[dt], 0, 0, 0);
                }
            }
            __builtin_amdgcn_s_setprio(0);
        }

        __syncthreads();   // all K/V reads done before overwrite
        if (more) {
#pragma unroll
            for (int i = 0; i < 4; i++) *(short8*)&klds[ksr * 136 + kc + i * 8] = krg[i];
#pragma unroll
            for (int i = 0; i < 4; i++) *(short8*)&vlds[vdr * 72 + vc + i * 8] = vrg[i];
        }
        __syncthreads();   // staging visible before next iteration's reads
    }

    // epilogue: scale (per-lane), transpose O^T -> O via LDS scratch
    const float scale = 0.022097086912079608f;   // 2048^-0.5
    float sc = scale / l_run;
    u16* ow = smem + wid * 4352;           // [t=32][d=128] stride 136
#pragma unroll
    for (int dt = 0; dt < 4; dt++)
#pragma unroll
        for (int gq = 0; gq < 4; gq++) {
            ushort4v pk;
            pk.x = f32_bf16(oacc[dt][gq * 4 + 0] * sc);
            pk.y = f32_bf16(oacc[dt][gq * 4 + 1] * sc);
            pk.z = f32_bf16(oacc[dt][gq * 4 + 2] * sc);
            pk.w = f32_bf16(oacc[dt][gq * 4 + 3] * sc);
            *(ushort4v*)&ow[l32 * 136 + dt * 32 + gq * 8 + hh * 4] = pk;
        }
    __syncthreads();   // transpose writes visible before read-back
    int tl = lane >> 4, dcol = (lane & 15) * 8;
#pragma unroll
    for (int ch = 0; ch < 8; ch++) {
        int t_local = tl + ch * 4;
        short8 ov = *(const short8*)&ow[t_local * 136 + dcol];
        *(short8*)&Oout[((size_t)(b * T_SEQ) + t0 + wid * 32 + t_local) * NE + hd * HD + dcol] = ov;
    }
}

// ---------------- launch ----------------
extern "C" void kernel_launch(void* const* d_in, const int* in_sizes, int n_in,
                              void* d_out, int out_size, void* d_ws, size_t ws_size,
                              hipStream_t stream) {
    const float* x  = (const float*)d_in[0];
    const float* Wq = (const float*)d_in[1];
    const float* bq = (const float*)d_in[2];
    const float* Wk = (const float*)d_in[3];
    const float* bk = (const float*)d_in[4];
    const float* Wv = (const float*)d_in[5];
    const float* bv = (const float*)d_in[6];
    const float* Wo = (const float*)d_in[7];
    const float* bo = (const float*)d_in[8];
    float* out = (float*)d_out;
    char* ws = (char*)d_ws;

    // aliasing: ao reuses xh (xh dead after QKV gemm); wot reuses wqt (dead after QKV gemm)
    u16* xh   = (u16*)(ws);                      // 16 MB   [also ao]
    u16* wqt  = (u16*)(ws + 16777216);           // 8 MB    [also wot]
    u16* wkt  = (u16*)(ws + 25165824);           // 2 MB
    u16* wvt  = (u16*)(ws + 27262976);           // 2 MB
    u16* qr   = (u16*)(ws + 29360128);           // 16 MB
    u16* kr   = (u16*)(ws + 46137344);           // 4 MB
    u16* vt   = (u16*)(ws + 50331648);           // 4 MB
    float* ctab = (float*)(ws + 54525952);       // 0.5 MB
    float* stab = (float*)(ws + 55050240);       // 0.5 MB
    u16* ao  = xh;
    u16* wot = wqt;

    conv_f16<<<8192, 256, 0, stream>>>(x, xh);
    transpose_convert<true><<<dim3(64, 64), dim3(32, 8), 0, stream>>>(Wq, wqt, 2048, 2048);
    transpose_convert<true><<<dim3(16, 64), dim3(32, 8), 0, stream>>>(Wk, wkt, 2048, 512);
    transpose_convert<true><<<dim3(16, 64), dim3(32, 8), 0, stream>>>(Wv, wvt, 2048, 512);
    rope_tab<<<512, 256, 0, stream>>>(ctab, stab);

    gemm_qkv<<<dim3(768), 256, 0, stream>>>(xh, wqt, wkt, wvt, bq, bk, bv,
                                            qr, kr, vt, ctab, stab);

    // Wo transpose after QKV gemm (wqt dead), before final gemm
    transpose_convert<false><<<dim3(64, 64), dim3(32, 8), 0, stream>>>(Wo, wot, 2048, 2048);

    attn_kernel<<<dim3(16, 32), 256, 0, stream>>>(qr, kr, vt, ao);

    gemm_out<<<dim3(32, 16), 256, 0, stream>>>(ao, wot, bo, out);
}